// Round 16
// baseline (160.137 us; speedup 1.0000x reference)
//
#include <hip/hip_runtime.h>

// SRM neuron: per-row 50-tap 'same' conv -> threshold -> refractory scan.
// B=4096 rows, T=16384.
// R16: f32 DIRECT conv with 16 independent accumulators (ILP=16, pure
//      issue-bound ~47us) replacing the f64 recurrence (R11-R15: 2-way-ILP
//      dependency chains, latency-bound at 37% VALUBusy). Geometry and all
//      other machinery identical to validated rounds:
//      - per-lane 17xf4 register window, guarded edges   (R13, absmax 0.0)
//      - E=16 FMA order o=-25..39 / jj=k+24-o guarded    (R10, absmax 0.0)
//      - taps+athr from K0 via scalar loads               (R9, absmax 0.0)
//      - bitmask-shuffle store transpose                  (R13, absmax 0.0)
//      - flags + K2 refractory fixup                      (R8+, absmax 0.0)
// Fallback: validated self-contained R7 kernel if ws too small.

#define TLEN   16384
#define NROWS  4096
#define KLEN   50
#define WPB    4        // waves per 256-thread block
#define SEGS   16       // segments per row
#define SEGLEN 1024     // elems per segment (64 lanes x 16)

// fixup / fallback geometry
#define FGRP  256
#define FNGRP 64
#define TILEW 336

// d_ws layout: float[0..49] taps, float[50] athr; flags int[] at byte 256.
#define WS_FLAGS_OFF 256
#define WS_NEED (WS_FLAGS_OFF + (size_t)NROWS * SEGS * sizeof(int))

typedef float f4 __attribute__((ext_vector_type(4)));

__device__ __forceinline__ float uniformf(float x) {
    return __int_as_float(__builtin_amdgcn_readfirstlane(__float_as_int(x)));
}

// compose: r[s] = then[first[s]]  (apply `first`, then `then`)
__device__ __forceinline__ int map_compose(int first, int then) {
    int r = 0;
#pragma unroll
    for (int s = 0; s < 4; ++s) {
        int a = (first >> (2 * s)) & 3;
        int b = (then >> (2 * a)) & 3;
        r |= b << (2 * s);
    }
    return r;
}

// Smallest float a with (v_reset + a/100.0f) >= v_th, via exact-predicate
// binary search over order-mapped float bits. cand == (acc >= athr) EXACTLY.
__device__ float solve_thresh(float v_reset, float v_th) {
    auto tokey = [](float f) {
        unsigned u = __float_as_uint(f);
        return (u & 0x80000000u) ? ~u : (u | 0x80000000u);
    };
    auto fromkey = [](unsigned k) {
        unsigned u = (k & 0x80000000u) ? (k & 0x7FFFFFFFu) : ~k;
        return __uint_as_float(u);
    };
    const float maxf = 3.402823466e38f;
    unsigned lo = tokey(-maxf), hi = tokey(maxf);
    if (!((v_reset + maxf / 100.0f) >= v_th))
        return __uint_as_float(0x7F800000u);  // pred never true -> +inf
    while (lo < hi) {
        unsigned mid = lo + ((hi - lo) >> 1);
        float a = fromkey(mid);
        if ((v_reset + a / 100.0f) >= v_th) hi = mid;
        else lo = mid + 1;
    }
    return fromkey(lo);
}

// ---------------- K0: taps + exact threshold -> d_ws ----------------
__global__ __launch_bounds__(64)
void setup_kernel(const float* __restrict__ p_tau_m,
                  const float* __restrict__ p_tau_s,
                  const float* __restrict__ p_v_th,
                  const float* __restrict__ p_v_reset,
                  float* __restrict__ wsf)
{
    const int lane = threadIdx.x & 63;
    const float tau_m = p_tau_m[0];
    const float tau_s = p_tau_s[0];

    // Per-lane tap value (same expression as reference / R1-R10).
    float ft = (float)lane;
    float v = (lane < KLEN) ? (expf(-ft / tau_m) - expf(-ft / tau_s)) : 0.0f;

    // Reference-ordered sequential sum t = 0..49 (bit-identical order).
    float ksum = 0.0f;
    for (int t = 0; t < KLEN; ++t)
        ksum += __shfl(v, t, 64);
    const float kden = ksum + 1e-10f;
    const float kt = v / kden;

    if (lane < KLEN) wsf[lane] = kt;
    if (lane == 0)   wsf[KLEN] = solve_thresh(p_v_reset[0], p_v_th[0]);
}

// ---------------- K1: direct conv (E=16, ILP=16) -> spikes + flags ----------------
__global__ __launch_bounds__(256)
void conv_kernel(const float* __restrict__ I,
                 const float* __restrict__ wsf,   // taps + athr (uniform loads)
                 float* __restrict__ out,
                 int* __restrict__ flags)
{
    const int lane = threadIdx.x & 63;
    const int wid  = threadIdx.x >> 6;
    const int wg   = blockIdx.x * WPB + wid;   // 0 .. NROWS*SEGS-1
    const int row  = wg >> 4;
    const int seg  = wg & 15;

    // Uniform loads -> SGPRs (no transcendentals/divides here; R9 pattern).
    float kt[KLEN];
#pragma unroll
    for (int t = 0; t < KLEN; ++t) kt[t] = wsf[t];
    const float athr = wsf[KLEN];

    const float* Irow = I + (size_t)row * TLEN;
    float* Orow = out + (size_t)row * TLEN;

    const int pos0 = seg * SEGLEN;
    const int t0   = pos0 + 16 * lane;   // lane's first output position
    // Output t0+k = sum_j kt[j] * x[t0+k+24-j]; window x[t0-25 .. t0+39].
    const int off  = t0 - 28;            // aligned base; WIN(m) = x[off+m]

    // ---- load window x[off .. off+67] (17 x f4; zeros outside the row) ----
    f4 wv[17];
    if (off >= 0 && off <= TLEN - 68) {
#pragma unroll
        for (int i = 0; i < 17; ++i)
            wv[i] = *(const f4*)(Irow + off + 4 * i);
    } else {
#pragma unroll
        for (int i = 0; i < 17; ++i) {
            const int idx = off + 4 * i;   // multiple of 4: f4 all-in or all-out
            wv[i] = (idx >= 0 && idx <= TLEN - 4)
                        ? *(const f4*)(Irow + idx)
                        : (f4){0.0f, 0.0f, 0.0f, 0.0f};
        }
    }
#define WIN(m) (wv[(m) >> 2][(m) & 3])

    // ---- direct conv: o ascending, per-output jj descending (R6/R10 order,
    //      validated bit-exact). 16 independent accumulators -> ILP=16. ----
    float acc[16];
#pragma unroll
    for (int k = 0; k < 16; ++k) acc[k] = 0.0f;
#pragma unroll
    for (int o = -25; o <= 39; ++o) {
        const float wx = WIN(o + 28);    // x[t0 + o]
#pragma unroll
        for (int k = 0; k < 16; ++k) {
            const int jj = k + 24 - o;
            if (jj >= 0 && jj < KLEN)
                acc[k] = fmaf(kt[jj], wx, acc[k]);
        }
    }
#undef WIN

    // ---- candidates vs exact threshold ----
    int m16 = 0;
#pragma unroll
    for (int k = 0; k < 16; ++k)
        m16 |= (acc[k] >= athr) ? (1 << k) : 0;
    if (t0 == 0) m16 &= ~1;   // spikes[0] forced 0 (loop starts at t=1)
    const int rowflag = m16;

    // ---- transpose to coalesced plain stores via shuffles (R13-validated) ----
    const int sh = 4 * (lane & 3);
#pragma unroll
    for (int j = 0; j < 4; ++j) {
        const int bits = __shfl(m16, (lane >> 2) + 16 * j, 64);
        f4 o0;
        o0.x = ((bits >> (sh + 0)) & 1) ? 1.0f : 0.0f;
        o0.y = ((bits >> (sh + 1)) & 1) ? 1.0f : 0.0f;
        o0.z = ((bits >> (sh + 2)) & 1) ? 1.0f : 0.0f;
        o0.w = ((bits >> (sh + 3)) & 1) ? 1.0f : 0.0f;
        *(f4*)(Orow + pos0 + 4 * lane + 256 * j) = o0;
    }

    // Deterministic flag write for every wave-group (0 or 1).
    const unsigned long long anyb = __ballot(rowflag != 0);
    if (lane == 0) flags[wg] = (anyb != 0ULL) ? 1 : 0;
}

// ---------------- K2: repair flagged rows with exact refractory scan ----------------
__global__ __launch_bounds__(256)
void fixup_kernel(const int* __restrict__ flags,
                  float* __restrict__ out)
{
    const int lane = threadIdx.x & 63;
    const int wid  = threadIdx.x >> 6;
    const int row  = blockIdx.x * WPB + wid;

    const int* pf = flags + SEGS * row;
    int any = 0;
#pragma unroll
    for (int j = 0; j < SEGS; ++j) any |= pf[j];
    if (any == 0) return;  // wave-uniform

    float* Orow = out + (size_t)row * TLEN;
    int r0 = 0;

    for (int g = 0; g < FNGRP; ++g) {
        f4 o = *(const f4*)(Orow + g * FGRP + 4 * lane);
        int cand[4];
        cand[0] = (o.x != 0.0f);
        cand[1] = (o.y != 0.0f);
        cand[2] = (o.z != 0.0f);
        cand[3] = (o.w != 0.0f);

        const int cm = cand[0] | cand[1] | cand[2] | cand[3];
        const unsigned long long anyc = __ballot(cm != 0);
        if (anyc == 0ULL) { r0 = 0; continue; }   // zeros already correct

        int s0 = 0, s1 = 1, s2 = 2, s3 = 3;
#pragma unroll
        for (int k = 0; k < 4; ++k) {
            const int c3 = cand[k] ? 3 : 0;
            s0 = (s0 > 0) ? (s0 - 1) : c3;
            s1 = (s1 > 0) ? (s1 - 1) : c3;
            s2 = (s2 > 0) ? (s2 - 1) : c3;
            s3 = (s3 > 0) ? (s3 - 1) : c3;
        }
        int P = s0 | (s1 << 2) | (s2 << 4) | (s3 << 6);

#pragma unroll
        for (int d = 1; d < 64; d <<= 1) {
            const int prev = __shfl_up(P, d, 64);
            const int comp = map_compose(prev, P);
            P = (lane >= d) ? comp : P;
        }
        const int Pprev = __shfl_up(P, 1, 64);
        const int sin0  = (lane == 0) ? r0 : ((Pprev >> (2 * r0)) & 3);
        const int Pfull = __shfl(P, 63, 64);
        r0 = (Pfull >> (2 * r0)) & 3;

        int s = sin0;
        float sp[4];
#pragma unroll
        for (int k = 0; k < 4; ++k) {
            const int spike = (s == 0) & cand[k];
            sp[k] = spike ? 1.0f : 0.0f;
            s = (s > 0) ? (s - 1) : (cand[k] ? 3 : 0);
        }
        f4 o0; o0.x = sp[0]; o0.y = sp[1]; o0.z = sp[2]; o0.w = sp[3];
        *(f4*)(Orow + g * FGRP + 4 * lane) = o0;
    }
}

// ---------------- Fallback: validated R7 single kernel ----------------
__global__ __launch_bounds__(256)
void srm_kernel(const float* __restrict__ I,
                const float* __restrict__ p_tau_m,
                const float* __restrict__ p_tau_s,
                const float* __restrict__ p_v_th,
                const float* __restrict__ p_v_reset,
                float* __restrict__ out)
{
    __shared__ __align__(16) float tile[WPB][2][TILEW];

    const int lane = threadIdx.x & 63;
    const int wid  = threadIdx.x >> 6;
    const int row  = blockIdx.x * WPB + wid;

    const float tau_m   = p_tau_m[0];
    const float tau_s   = p_tau_s[0];
    const float v_th    = p_v_th[0];
    const float v_reset = p_v_reset[0];

    float ku[KLEN];
    float ksum = 0.0f;
#pragma unroll
    for (int t = 0; t < KLEN; ++t) {
        float ft = (float)t;
        float v = expf(-ft / tau_m) - expf(-ft / tau_s);
        ksum += v;
        ku[t] = uniformf(v);
    }
    const float kden = uniformf(ksum + 1e-10f);
    float kt[KLEN];
#pragma unroll
    for (int t = 0; t < KLEN; ++t) kt[t] = uniformf(ku[t] / kden);

    const float athr = uniformf(solve_thresh(v_reset, v_th));

    const float* Irow = I + (size_t)row * TLEN;
    float* Orow = out + (size_t)row * TLEN;

    float Cv[4], Nv[4], Lv[4];
    {
        f4 a = *(const f4*)(Irow + 0 * FGRP + 4 * lane);
        Cv[0] = a.x; Cv[1] = a.y; Cv[2] = a.z; Cv[3] = a.w;
        f4 c = *(const f4*)(Irow + 1 * FGRP + 4 * lane);
        Nv[0] = c.x; Nv[1] = c.y; Nv[2] = c.z; Nv[3] = c.w;
    }

    if (lane < 8) {
        f4 z = (f4){0.0f, 0.0f, 0.0f, 0.0f};
        *(f4*)&tile[wid][0][4 * lane] = z;
    }
    {
        f4 c; c.x = Cv[0]; c.y = Cv[1]; c.z = Cv[2]; c.w = Cv[3];
        *(f4*)&tile[wid][0][32 + 4 * lane] = c;
    }

    int r0 = 0;

    for (int g = 0; g < FNGRP; ++g) {
        const int cur = g & 1;
        const int nxt = cur ^ 1;

        if (g + 2 < FNGRP) {
            f4 a = *(const f4*)(Irow + (size_t)(g + 2) * FGRP + 4 * lane);
            Lv[0] = a.x; Lv[1] = a.y; Lv[2] = a.z; Lv[3] = a.w;
        } else {
            Lv[0] = Lv[1] = Lv[2] = Lv[3] = 0.0f;
        }

        f4 nv; nv.x = Nv[0]; nv.y = Nv[1]; nv.z = Nv[2]; nv.w = Nv[3];
        if (lane < 8)
            *(f4*)&tile[wid][cur][288 + 4 * lane] = nv;
        *(f4*)&tile[wid][nxt][32 + 4 * lane] = nv;
        if (lane >= 56) {
            f4 cv; cv.x = Cv[0]; cv.y = Cv[1]; cv.z = Cv[2]; cv.w = Cv[3];
            *(f4*)&tile[wid][nxt][4 * (lane - 56)] = cv;
        }

        f4 wv[15];
#pragma unroll
        for (int i = 0; i < 15; ++i)
            wv[i] = *(const f4*)&tile[wid][cur][4 * lane + 4 + 4 * i];
#define WIN(m) (wv[(m) >> 2][(m) & 3])

        float acc[4];
        acc[0] = acc[1] = acc[2] = acc[3] = 0.0f;
#pragma unroll
        for (int o = -25; o <= 27; ++o) {
            const float w = WIN(o + 28);
#pragma unroll
            for (int k = 0; k < 4; ++k) {
                const int jj = k + 24 - o;
                if (jj >= 0 && jj < KLEN)
                    acc[k] = fmaf(kt[jj], w, acc[k]);
            }
        }
#undef WIN

        const int tb = g * FGRP + 4 * lane;
        int cand[4];
#pragma unroll
        for (int k = 0; k < 4; ++k)
            cand[k] = (acc[k] >= athr) ? 1 : 0;
        cand[0] &= (tb != 0);

        const int cm = cand[0] | cand[1] | cand[2] | cand[3];
        const unsigned long long anyc = __ballot(cm != 0);

        f4 o0;
        if (anyc == 0ULL) {
            o0 = (f4){0.0f, 0.0f, 0.0f, 0.0f};
            r0 = 0;
        } else {
            int s0 = 0, s1 = 1, s2 = 2, s3 = 3;
#pragma unroll
            for (int k = 0; k < 4; ++k) {
                const int c3 = cand[k] ? 3 : 0;
                s0 = (s0 > 0) ? (s0 - 1) : c3;
                s1 = (s1 > 0) ? (s1 - 1) : c3;
                s2 = (s2 > 0) ? (s2 - 1) : c3;
                s3 = (s3 > 0) ? (s3 - 1) : c3;
            }
            int P = s0 | (s1 << 2) | (s2 << 4) | (s3 << 6);
#pragma unroll
            for (int d = 1; d < 64; d <<= 1) {
                const int prev = __shfl_up(P, d, 64);
                const int comp = map_compose(prev, P);
                P = (lane >= d) ? comp : P;
            }
            const int Pprev = __shfl_up(P, 1, 64);
            const int sin0  = (lane == 0) ? r0 : ((Pprev >> (2 * r0)) & 3);
            const int Pfull = __shfl(P, 63, 64);
            r0 = (Pfull >> (2 * r0)) & 3;

            int s = sin0;
            float sp[4];
#pragma unroll
            for (int k = 0; k < 4; ++k) {
                const int spike = (s == 0) & cand[k];
                sp[k] = spike ? 1.0f : 0.0f;
                s = (s > 0) ? (s - 1) : (cand[k] ? 3 : 0);
            }
            o0.x = sp[0]; o0.y = sp[1]; o0.z = sp[2]; o0.w = sp[3];
        }

        *(f4*)(Orow + tb) = o0;

#pragma unroll
        for (int j = 0; j < 4; ++j) { Cv[j] = Nv[j]; Nv[j] = Lv[j]; }
    }
}

extern "C" void kernel_launch(void* const* d_in, const int* in_sizes, int n_in,
                              void* d_out, int out_size, void* d_ws, size_t ws_size,
                              hipStream_t stream) {
    const float* I       = (const float*)d_in[0];
    const float* tau_m   = (const float*)d_in[1];
    const float* tau_s   = (const float*)d_in[2];
    const float* v_th    = (const float*)d_in[3];
    const float* v_reset = (const float*)d_in[4];
    float* out = (float*)d_out;

    if (ws_size >= WS_NEED) {
        float* wsf  = (float*)d_ws;
        int* flags  = (int*)((char*)d_ws + WS_FLAGS_OFF);
        setup_kernel<<<dim3(1), dim3(64), 0, stream>>>(
            tau_m, tau_s, v_th, v_reset, wsf);
        conv_kernel<<<dim3(NROWS * SEGS / WPB), dim3(256), 0, stream>>>(
            I, wsf, out, flags);
        fixup_kernel<<<dim3(NROWS / WPB), dim3(256), 0, stream>>>(flags, out);
    } else {
        srm_kernel<<<dim3(NROWS / WPB), dim3(256), 0, stream>>>(
            I, tau_m, tau_s, v_th, v_reset, out);
    }
}

// Round 17
// 150.705 us; speedup vs baseline: 1.0626x; 1.0626x over previous
//
#include <hip/hip_runtime.h>

// SRM neuron: per-row 50-tap 'same' conv -> threshold -> refractory scan.
// B=4096 rows, T=16384.
// R17: R14/R15/R16 (three different compute schemes) all pinned at ~150us ->
//      compute exonerated; shared factor is the per-lane window loads
//      (64B lane stride: every dwordx4 touches 64 DISTINCT cache lines ->
//      TA/L1 line-rate wall, ~71M line-requests). Fix: coalesced staging
//      (6 loads, 16 lines/instr) into a wave-private LDS tile, window reads
//      from LDS with XOR swizzle p = b ^ ((b>>4)&7) (<=2-way conflicts).
//      Conv body / threshold / transpose / flags / fixup VERBATIM R16
//      (absmax 0.0). Same-wave DS ordering needs no barrier (R7-R9).
// Fallback: validated self-contained R7 kernel if ws too small.

#define TLEN   16384
#define NROWS  4096
#define KLEN   50
#define WPB    4        // waves per 256-thread block
#define SEGS   16       // segments per row
#define SEGLEN 1024     // elems per segment (64 lanes x 16)
#define TILEB  272      // 16B blocks per wave tile (269 used, pad to mult of 16)

// fixup / fallback geometry
#define FGRP  256
#define FNGRP 64
#define TILEW 336

// d_ws layout: float[0..49] taps, float[50] athr; flags int[] at byte 256.
#define WS_FLAGS_OFF 256
#define WS_NEED (WS_FLAGS_OFF + (size_t)NROWS * SEGS * sizeof(int))

typedef float f4 __attribute__((ext_vector_type(4)));

__device__ __forceinline__ float uniformf(float x) {
    return __int_as_float(__builtin_amdgcn_readfirstlane(__float_as_int(x)));
}

// LDS block swizzle: spreads 4-block-strided reads across bank quads.
__device__ __forceinline__ int swz(int b) { return b ^ ((b >> 4) & 7); }

// compose: r[s] = then[first[s]]  (apply `first`, then `then`)
__device__ __forceinline__ int map_compose(int first, int then) {
    int r = 0;
#pragma unroll
    for (int s = 0; s < 4; ++s) {
        int a = (first >> (2 * s)) & 3;
        int b = (then >> (2 * a)) & 3;
        r |= b << (2 * s);
    }
    return r;
}

// Smallest float a with (v_reset + a/100.0f) >= v_th, via exact-predicate
// binary search over order-mapped float bits. cand == (acc >= athr) EXACTLY.
__device__ float solve_thresh(float v_reset, float v_th) {
    auto tokey = [](float f) {
        unsigned u = __float_as_uint(f);
        return (u & 0x80000000u) ? ~u : (u | 0x80000000u);
    };
    auto fromkey = [](unsigned k) {
        unsigned u = (k & 0x80000000u) ? (k & 0x7FFFFFFFu) : ~k;
        return __uint_as_float(u);
    };
    const float maxf = 3.402823466e38f;
    unsigned lo = tokey(-maxf), hi = tokey(maxf);
    if (!((v_reset + maxf / 100.0f) >= v_th))
        return __uint_as_float(0x7F800000u);  // pred never true -> +inf
    while (lo < hi) {
        unsigned mid = lo + ((hi - lo) >> 1);
        float a = fromkey(mid);
        if ((v_reset + a / 100.0f) >= v_th) hi = mid;
        else lo = mid + 1;
    }
    return fromkey(lo);
}

// ---------------- K0: taps + exact threshold -> d_ws ----------------
__global__ __launch_bounds__(64)
void setup_kernel(const float* __restrict__ p_tau_m,
                  const float* __restrict__ p_tau_s,
                  const float* __restrict__ p_v_th,
                  const float* __restrict__ p_v_reset,
                  float* __restrict__ wsf)
{
    const int lane = threadIdx.x & 63;
    const float tau_m = p_tau_m[0];
    const float tau_s = p_tau_s[0];

    float ft = (float)lane;
    float v = (lane < KLEN) ? (expf(-ft / tau_m) - expf(-ft / tau_s)) : 0.0f;

    // Reference-ordered sequential sum t = 0..49 (bit-identical order).
    float ksum = 0.0f;
    for (int t = 0; t < KLEN; ++t)
        ksum += __shfl(v, t, 64);
    const float kden = ksum + 1e-10f;
    const float kt = v / kden;

    if (lane < KLEN) wsf[lane] = kt;
    if (lane == 0)   wsf[KLEN] = solve_thresh(p_v_reset[0], p_v_th[0]);
}

// ---------------- K1: LDS-staged direct conv (E=16) -> spikes + flags ----------------
__global__ __launch_bounds__(256)
void conv_kernel(const float* __restrict__ I,
                 const float* __restrict__ wsf,   // taps + athr (uniform loads)
                 float* __restrict__ out,
                 int* __restrict__ flags)
{
    __shared__ __align__(16) float tile[WPB][TILEB * 4];

    const int lane = threadIdx.x & 63;
    const int wid  = threadIdx.x >> 6;
    const int wg   = blockIdx.x * WPB + wid;   // 0 .. NROWS*SEGS-1
    const int row  = wg >> 4;
    const int seg  = wg & 15;

    // Uniform loads -> SGPRs (no transcendentals/divides; R9 pattern).
    float kt[KLEN];
#pragma unroll
    for (int t = 0; t < KLEN; ++t) kt[t] = wsf[t];
    const float athr = wsf[KLEN];

    const float* Irow = I + (size_t)row * TLEN;
    float* Orow = out + (size_t)row * TLEN;

    const int pos0 = seg * SEGLEN;
    const int t0   = pos0 + 16 * lane;   // lane's first output position

    char* tb_ = (char*)&tile[wid][0];

    // ---- stage segment + halos into LDS (coalesced global loads) ----
    // Tile logical blocks (16B each): [0..6] halo-left x[pos0-28..pos0-1],
    // [7..262] main x[pos0..pos0+1023], [263..268] halo-right
    // x[pos0+1024..pos0+1047]. Physical block = swz(logical).
#pragma unroll
    for (int j = 0; j < 4; ++j) {
        f4 v = *(const f4*)(Irow + pos0 + 4 * lane + 256 * j);
        *(f4*)(tb_ + (swz(7 + lane + 64 * j) << 4)) = v;
    }
    if (lane < 7) {
        f4 h = (f4){0.0f, 0.0f, 0.0f, 0.0f};
        if (pos0 > 0) h = *(const f4*)(Irow + pos0 - 28 + 4 * lane);
        *(f4*)(tb_ + (swz(lane) << 4)) = h;
    }
    if (lane >= 57 && lane < 63) {
        f4 h = (f4){0.0f, 0.0f, 0.0f, 0.0f};
        if (pos0 + SEGLEN < TLEN)
            h = *(const f4*)(Irow + pos0 + SEGLEN + 4 * (lane - 57));
        *(f4*)(tb_ + (swz(lane + 206) << 4)) = h;   // 263 + (lane-57)
    }
    // Same-wave DS ops execute in program order; reads below see the writes
    // (wave-private tile, no barrier needed -- R7-R9 validated).

    // ---- window read from LDS: wv[i] = x[t0-28+4i .. +3] (17 b128 reads) ----
    f4 wv[17];
#pragma unroll
    for (int i = 0; i < 17; ++i)
        wv[i] = *(const f4*)(tb_ + (swz(4 * lane + i) << 4));
#define WIN(m) (wv[(m) >> 2][(m) & 3])

    // ---- direct conv: o ascending, per-output jj descending (R6/R10/R16
    //      order, validated bit-exact). 16 independent accumulators. ----
    float acc[16];
#pragma unroll
    for (int k = 0; k < 16; ++k) acc[k] = 0.0f;
#pragma unroll
    for (int o = -25; o <= 39; ++o) {
        const float wx = WIN(o + 28);    // x[t0 + o]
#pragma unroll
        for (int k = 0; k < 16; ++k) {
            const int jj = k + 24 - o;
            if (jj >= 0 && jj < KLEN)
                acc[k] = fmaf(kt[jj], wx, acc[k]);
        }
    }
#undef WIN

    // ---- candidates vs exact threshold ----
    int m16 = 0;
#pragma unroll
    for (int k = 0; k < 16; ++k)
        m16 |= (acc[k] >= athr) ? (1 << k) : 0;
    if (t0 == 0) m16 &= ~1;   // spikes[0] forced 0 (loop starts at t=1)
    const int rowflag = m16;

    // ---- transpose to coalesced plain stores via shuffles (R13/R16) ----
    const int sh = 4 * (lane & 3);
#pragma unroll
    for (int j = 0; j < 4; ++j) {
        const int bits = __shfl(m16, (lane >> 2) + 16 * j, 64);
        f4 o0;
        o0.x = ((bits >> (sh + 0)) & 1) ? 1.0f : 0.0f;
        o0.y = ((bits >> (sh + 1)) & 1) ? 1.0f : 0.0f;
        o0.z = ((bits >> (sh + 2)) & 1) ? 1.0f : 0.0f;
        o0.w = ((bits >> (sh + 3)) & 1) ? 1.0f : 0.0f;
        *(f4*)(Orow + pos0 + 4 * lane + 256 * j) = o0;
    }

    // Deterministic flag write for every wave-group (0 or 1).
    const unsigned long long anyb = __ballot(rowflag != 0);
    if (lane == 0) flags[wg] = (anyb != 0ULL) ? 1 : 0;
}

// ---------------- K2: repair flagged rows with exact refractory scan ----------------
__global__ __launch_bounds__(256)
void fixup_kernel(const int* __restrict__ flags,
                  float* __restrict__ out)
{
    const int lane = threadIdx.x & 63;
    const int wid  = threadIdx.x >> 6;
    const int row  = blockIdx.x * WPB + wid;

    const int* pf = flags + SEGS * row;
    int any = 0;
#pragma unroll
    for (int j = 0; j < SEGS; ++j) any |= pf[j];
    if (any == 0) return;  // wave-uniform

    float* Orow = out + (size_t)row * TLEN;
    int r0 = 0;

    for (int g = 0; g < FNGRP; ++g) {
        f4 o = *(const f4*)(Orow + g * FGRP + 4 * lane);
        int cand[4];
        cand[0] = (o.x != 0.0f);
        cand[1] = (o.y != 0.0f);
        cand[2] = (o.z != 0.0f);
        cand[3] = (o.w != 0.0f);

        const int cm = cand[0] | cand[1] | cand[2] | cand[3];
        const unsigned long long anyc = __ballot(cm != 0);
        if (anyc == 0ULL) { r0 = 0; continue; }   // zeros already correct

        int s0 = 0, s1 = 1, s2 = 2, s3 = 3;
#pragma unroll
        for (int k = 0; k < 4; ++k) {
            const int c3 = cand[k] ? 3 : 0;
            s0 = (s0 > 0) ? (s0 - 1) : c3;
            s1 = (s1 > 0) ? (s1 - 1) : c3;
            s2 = (s2 > 0) ? (s2 - 1) : c3;
            s3 = (s3 > 0) ? (s3 - 1) : c3;
        }
        int P = s0 | (s1 << 2) | (s2 << 4) | (s3 << 6);

#pragma unroll
        for (int d = 1; d < 64; d <<= 1) {
            const int prev = __shfl_up(P, d, 64);
            const int comp = map_compose(prev, P);
            P = (lane >= d) ? comp : P;
        }
        const int Pprev = __shfl_up(P, 1, 64);
        const int sin0  = (lane == 0) ? r0 : ((Pprev >> (2 * r0)) & 3);
        const int Pfull = __shfl(P, 63, 64);
        r0 = (Pfull >> (2 * r0)) & 3;

        int s = sin0;
        float sp[4];
#pragma unroll
        for (int k = 0; k < 4; ++k) {
            const int spike = (s == 0) & cand[k];
            sp[k] = spike ? 1.0f : 0.0f;
            s = (s > 0) ? (s - 1) : (cand[k] ? 3 : 0);
        }
        f4 o0; o0.x = sp[0]; o0.y = sp[1]; o0.z = sp[2]; o0.w = sp[3];
        *(f4*)(Orow + g * FGRP + 4 * lane) = o0;
    }
}

// ---------------- Fallback: validated R7 single kernel ----------------
__global__ __launch_bounds__(256)
void srm_kernel(const float* __restrict__ I,
                const float* __restrict__ p_tau_m,
                const float* __restrict__ p_tau_s,
                const float* __restrict__ p_v_th,
                const float* __restrict__ p_v_reset,
                float* __restrict__ out)
{
    __shared__ __align__(16) float tile[WPB][2][TILEW];

    const int lane = threadIdx.x & 63;
    const int wid  = threadIdx.x >> 6;
    const int row  = blockIdx.x * WPB + wid;

    const float tau_m   = p_tau_m[0];
    const float tau_s   = p_tau_s[0];
    const float v_th    = p_v_th[0];
    const float v_reset = p_v_reset[0];

    float ku[KLEN];
    float ksum = 0.0f;
#pragma unroll
    for (int t = 0; t < KLEN; ++t) {
        float ft = (float)t;
        float v = expf(-ft / tau_m) - expf(-ft / tau_s);
        ksum += v;
        ku[t] = uniformf(v);
    }
    const float kden = uniformf(ksum + 1e-10f);
    float kt[KLEN];
#pragma unroll
    for (int t = 0; t < KLEN; ++t) kt[t] = uniformf(ku[t] / kden);

    const float athr = uniformf(solve_thresh(v_reset, v_th));

    const float* Irow = I + (size_t)row * TLEN;
    float* Orow = out + (size_t)row * TLEN;

    float Cv[4], Nv[4], Lv[4];
    {
        f4 a = *(const f4*)(Irow + 0 * FGRP + 4 * lane);
        Cv[0] = a.x; Cv[1] = a.y; Cv[2] = a.z; Cv[3] = a.w;
        f4 c = *(const f4*)(Irow + 1 * FGRP + 4 * lane);
        Nv[0] = c.x; Nv[1] = c.y; Nv[2] = c.z; Nv[3] = c.w;
    }

    if (lane < 8) {
        f4 z = (f4){0.0f, 0.0f, 0.0f, 0.0f};
        *(f4*)&tile[wid][0][4 * lane] = z;
    }
    {
        f4 c; c.x = Cv[0]; c.y = Cv[1]; c.z = Cv[2]; c.w = Cv[3];
        *(f4*)&tile[wid][0][32 + 4 * lane] = c;
    }

    int r0 = 0;

    for (int g = 0; g < FNGRP; ++g) {
        const int cur = g & 1;
        const int nxt = cur ^ 1;

        if (g + 2 < FNGRP) {
            f4 a = *(const f4*)(Irow + (size_t)(g + 2) * FGRP + 4 * lane);
            Lv[0] = a.x; Lv[1] = a.y; Lv[2] = a.z; Lv[3] = a.w;
        } else {
            Lv[0] = Lv[1] = Lv[2] = Lv[3] = 0.0f;
        }

        f4 nv; nv.x = Nv[0]; nv.y = Nv[1]; nv.z = Nv[2]; nv.w = Nv[3];
        if (lane < 8)
            *(f4*)&tile[wid][cur][288 + 4 * lane] = nv;
        *(f4*)&tile[wid][nxt][32 + 4 * lane] = nv;
        if (lane >= 56) {
            f4 cv; cv.x = Cv[0]; cv.y = Cv[1]; cv.z = Cv[2]; cv.w = Cv[3];
            *(f4*)&tile[wid][nxt][4 * (lane - 56)] = cv;
        }

        f4 wv[15];
#pragma unroll
        for (int i = 0; i < 15; ++i)
            wv[i] = *(const f4*)&tile[wid][cur][4 * lane + 4 + 4 * i];
#define WIN(m) (wv[(m) >> 2][(m) & 3])

        float acc[4];
        acc[0] = acc[1] = acc[2] = acc[3] = 0.0f;
#pragma unroll
        for (int o = -25; o <= 27; ++o) {
            const float w = WIN(o + 28);
#pragma unroll
            for (int k = 0; k < 4; ++k) {
                const int jj = k + 24 - o;
                if (jj >= 0 && jj < KLEN)
                    acc[k] = fmaf(kt[jj], w, acc[k]);
            }
        }
#undef WIN

        const int tb = g * FGRP + 4 * lane;
        int cand[4];
#pragma unroll
        for (int k = 0; k < 4; ++k)
            cand[k] = (acc[k] >= athr) ? 1 : 0;
        cand[0] &= (tb != 0);

        const int cm = cand[0] | cand[1] | cand[2] | cand[3];
        const unsigned long long anyc = __ballot(cm != 0);

        f4 o0;
        if (anyc == 0ULL) {
            o0 = (f4){0.0f, 0.0f, 0.0f, 0.0f};
            r0 = 0;
        } else {
            int s0 = 0, s1 = 1, s2 = 2, s3 = 3;
#pragma unroll
            for (int k = 0; k < 4; ++k) {
                const int c3 = cand[k] ? 3 : 0;
                s0 = (s0 > 0) ? (s0 - 1) : c3;
                s1 = (s1 > 0) ? (s1 - 1) : c3;
                s2 = (s2 > 0) ? (s2 - 1) : c3;
                s3 = (s3 > 0) ? (s3 - 1) : c3;
            }
            int P = s0 | (s1 << 2) | (s2 << 4) | (s3 << 6);
#pragma unroll
            for (int d = 1; d < 64; d <<= 1) {
                const int prev = __shfl_up(P, d, 64);
                const int comp = map_compose(prev, P);
                P = (lane >= d) ? comp : P;
            }
            const int Pprev = __shfl_up(P, 1, 64);
            const int sin0  = (lane == 0) ? r0 : ((Pprev >> (2 * r0)) & 3);
            const int Pfull = __shfl(P, 63, 64);
            r0 = (Pfull >> (2 * r0)) & 3;

            int s = sin0;
            float sp[4];
#pragma unroll
            for (int k = 0; k < 4; ++k) {
                const int spike = (s == 0) & cand[k];
                sp[k] = spike ? 1.0f : 0.0f;
                s = (s > 0) ? (s - 1) : (cand[k] ? 3 : 0);
            }
            o0.x = sp[0]; o0.y = sp[1]; o0.z = sp[2]; o0.w = sp[3];
        }

        *(f4*)(Orow + tb) = o0;

#pragma unroll
        for (int j = 0; j < 4; ++j) { Cv[j] = Nv[j]; Nv[j] = Lv[j]; }
    }
}

extern "C" void kernel_launch(void* const* d_in, const int* in_sizes, int n_in,
                              void* d_out, int out_size, void* d_ws, size_t ws_size,
                              hipStream_t stream) {
    const float* I       = (const float*)d_in[0];
    const float* tau_m   = (const float*)d_in[1];
    const float* tau_s   = (const float*)d_in[2];
    const float* v_th    = (const float*)d_in[3];
    const float* v_reset = (const float*)d_in[4];
    float* out = (float*)d_out;

    if (ws_size >= WS_NEED) {
        float* wsf  = (float*)d_ws;
        int* flags  = (int*)((char*)d_ws + WS_FLAGS_OFF);
        setup_kernel<<<dim3(1), dim3(64), 0, stream>>>(
            tau_m, tau_s, v_th, v_reset, wsf);
        conv_kernel<<<dim3(NROWS * SEGS / WPB), dim3(256), 0, stream>>>(
            I, wsf, out, flags);
        fixup_kernel<<<dim3(NROWS / WPB), dim3(256), 0, stream>>>(flags, out);
    } else {
        srm_kernel<<<dim3(NROWS / WPB), dim3(256), 0, stream>>>(
            I, tau_m, tau_s, v_th, v_reset, out);
    }
}